// Round 4
// baseline (14426.845 us; speedup 1.0000x reference)
//
#include <hip/hip_runtime.h>

// Fused 3-layer tanh RNN (B=131072, T=6, V=31) + linear + tanh + softmax.
// Weights+biases staged in LDS once per block (packed 64-float rows
// [wi(31)|bsum|wh(31)|pad]); all 64 lanes read the same LDS address ->
// broadcast, no bank conflicts. State in VGPRs.
//
// LAUNCH BOUNDS (measured, do not change): (256,1) -> 240 VGPR, no spill
// (R2). (256,2) -> compiler caps at 128 VGPR -> gigabytes of scratch spill
// traffic (R1: 4 ms, R3: 7.8 ms). Hardware still runs 2 waves/SIMD at
// VGPR<=256, so (256,1) loses no occupancy.

#define VD 31
#define TD 6
#define LD 3
#define ROWF 64                    // floats per packed row
#define NROWS (LD * VD + VD)       // 93 RNN rows + 31 linear rows = 124
#define SMEMF (NROWS * ROWF)       // 7936 floats = 31 KB

__device__ __forceinline__ float fast_tanh(float x) {
    x = fminf(fmaxf(x, -15.0f), 15.0f);
    float e = __expf(2.0f * x);
    return (e - 1.0f) * __builtin_amdgcn_rcpf(e + 1.0f);
}

// One RNN layer step: hout[j] = tanh(bsum[j] + wi[j]·x + wh[j]·h)
__device__ __forceinline__ void layer_step_lds(
    const float* __restrict__ wbase,
    const float (&x)[VD], const float (&hin)[VD], float (&hout)[VD])
{
#pragma unroll
    for (int j = 0; j < VD; ++j) {
        const float* w = wbase + j * ROWF;
        float acc_i = w[31];            // precombined bih+bhh
        float acc_h = 0.0f;
#pragma unroll
        for (int k = 0; k < VD; ++k) acc_i = fmaf(w[k], x[k], acc_i);
#pragma unroll
        for (int k = 0; k < VD; ++k) acc_h = fmaf(w[32 + k], hin[k], acc_h);
        hout[j] = fast_tanh(acc_i + acc_h);
    }
}

__global__ __launch_bounds__(256, 1) void rnn_fused(
    const float* __restrict__ inp,   // [B, T, V]
    const float* __restrict__ h0,    // [L, B, V]
    const float* __restrict__ Wih,   // [L, V, V]
    const float* __restrict__ Whh,   // [L, V, V]
    const float* __restrict__ bih,   // [L, V]
    const float* __restrict__ bhh,   // [L, V]
    const float* __restrict__ Wlin,  // [V, V]
    const float* __restrict__ blin,  // [V]
    float* __restrict__ out,         // [B, V]
    int B)
{
    __shared__ __align__(16) float smem[SMEMF];

    // ---- cooperative staging: pack weights + combined biases into LDS ----
    for (int idx = threadIdx.x; idx < SMEMF; idx += 256) {
        const int row = idx >> 6;       // /ROWF
        const int e   = idx & (ROWF - 1);
        float v = 0.0f;
        if (row < LD * VD) {
            const int l = row / VD;
            const int j = row - l * VD;
            if (e < VD)            v = Wih[(l * VD + j) * VD + e];
            else if (e == VD)      v = bih[l * VD + j] + bhh[l * VD + j];
            else if (e < 32 + VD)  v = Whh[(l * VD + j) * VD + (e - 32)];
        } else {
            const int j = row - LD * VD;
            if (e < VD)            v = Wlin[j * VD + e];
            else if (e == VD)      v = blin[j];
        }
        smem[idx] = v;
    }
    __syncthreads();

    const int b = blockIdx.x * blockDim.x + threadIdx.x;
    if (b >= B) return;

    float h1[VD], h2[VD], h3[VD];
    {
        const float* p0 = h0 + (size_t)b * VD;
        const float* p1 = h0 + ((size_t)B + b) * VD;
        const float* p2 = h0 + ((size_t)2 * B + b) * VD;
#pragma unroll
        for (int j = 0; j < VD; ++j) { h1[j] = p0[j]; h2[j] = p1[j]; h3[j] = p2[j]; }
    }

    const float* xb = inp + (size_t)b * TD * VD;
    const float* l0 = smem;
    const float* l1 = smem + VD * ROWF;
    const float* l2 = smem + 2 * VD * ROWF;
    const float* lf = smem + 3 * VD * ROWF;

    for (int t = 0; t < TD; ++t) {
        float xt[VD];
#pragma unroll
        for (int k = 0; k < VD; ++k) xt[k] = xb[t * VD + k];

        float tmp[VD];
        layer_step_lds(l0, xt, h1, tmp);
#pragma unroll
        for (int j = 0; j < VD; ++j) h1[j] = tmp[j];
        layer_step_lds(l1, h1, h2, tmp);
#pragma unroll
        for (int j = 0; j < VD; ++j) h2[j] = tmp[j];
        layer_step_lds(l2, h2, h3, tmp);
#pragma unroll
        for (int j = 0; j < VD; ++j) h3[j] = tmp[j];
    }

    // final linear + tanh
    float logits[VD];
#pragma unroll
    for (int j = 0; j < VD; ++j) {
        const float* w = lf + j * ROWF;
        float acc = w[31];              // blin
#pragma unroll
        for (int k = 0; k < VD; ++k) acc = fmaf(w[k], h3[k], acc);
        logits[j] = fast_tanh(acc);
    }

    // softmax over 31 logits
    float m = logits[0];
#pragma unroll
    for (int j = 1; j < VD; ++j) m = fmaxf(m, logits[j]);
    float e[VD];
    float s = 0.0f;
#pragma unroll
    for (int j = 0; j < VD; ++j) { e[j] = __expf(logits[j] - m); s += e[j]; }
    const float inv = __builtin_amdgcn_rcpf(s);
    float* ob = out + (size_t)b * VD;
#pragma unroll
    for (int j = 0; j < VD; ++j) ob[j] = e[j] * inv;
}

extern "C" void kernel_launch(void* const* d_in, const int* in_sizes, int n_in,
                              void* d_out, int out_size, void* d_ws, size_t ws_size,
                              hipStream_t stream) {
    const float* inp  = (const float*)d_in[0];
    const float* h0   = (const float*)d_in[1];
    const float* Wih  = (const float*)d_in[2];
    const float* Whh  = (const float*)d_in[3];
    const float* bih  = (const float*)d_in[4];
    const float* bhh  = (const float*)d_in[5];
    const float* Wlin = (const float*)d_in[6];
    const float* blin = (const float*)d_in[7];
    float* out = (float*)d_out;

    const int B = in_sizes[0] / (TD * VD);
    const int block = 256;
    const int grid = (B + block - 1) / block;
    rnn_fused<<<grid, block, 0, stream>>>(inp, h0, Wih, Whh, bih, bhh, Wlin, blin, out, B);
}

// Round 5
// 240.608 us; speedup vs baseline: 59.9600x; 59.9600x over previous
//
#include <hip/hip_runtime.h>

// Fused 3-layer tanh RNN (B=131072, T=6, V=31) + linear + tanh + softmax,
// reformulated on MFMA (mfma_f32_16x16x32_bf16).
//
// Per wave: 16 batch rows. Weights live as stationary B-fragments in VGPRs
// (14 frags = 56 VGPRs), loaded once -- this removes the per-MAC weight
// operand delivery that caused R1-R4's spills/latency (scalar path peaked
// at 1222 us with 7x VALU bloat). Per layer-step: 4 MFMAs (2 N-tiles x
// {x-part, h-part}, K=32, k=31 zero pad), tanh epilogue, C->A relayout via
// per-wave LDS ping-pong (write b16 in C/D layout col=lane&15,
// row=quad*4+reg; read ds_read_b128 in A layout [m=lane&15][k=quad*8+j]).
// Neuron pad col 31: B-frag rows zeroed + zero bias -> tanh(0)=0 self-
// maintaining. Final linear + softmax via __shfl_xor width-16 reduction.

#define VD 31
#define TD 6
#define LROW 40                 // LDS row stride in shorts (80 B): quads land
                                // 2-way/4-way max on banks; reads 16B-aligned
#define LBUF (16 * LROW)

typedef __attribute__((ext_vector_type(8))) short bf16x8;
typedef __attribute__((ext_vector_type(4))) float f32x4;

__device__ __forceinline__ short f2bf(float f) {
    // round-to-nearest-even fp32 -> bf16
    unsigned u = __float_as_uint(f);
    unsigned r = (u + 0x7fffu + ((u >> 16) & 1u)) >> 16;
    return (short)r;
}

__device__ __forceinline__ float fast_tanh(float x) {
    x = fminf(fmaxf(x, -15.0f), 15.0f);
    float e = __expf(2.0f * x);
    return (e - 1.0f) * __builtin_amdgcn_rcpf(e + 1.0f);
}

// B-fragment of W^T (B[k][n] = W[n][k]); rows n>=31 and cols k>=31 are zero.
__device__ __forceinline__ bf16x8 load_wfrag(const float* __restrict__ W,
                                             int nn, int k0) {
    bf16x8 r;
#pragma unroll
    for (int j = 0; j < 8; ++j) {
        int k = k0 + j;
        float v = (nn < VD && k < VD) ? W[nn * VD + k] : 0.0f;
        r[j] = f2bf(v);
    }
    return r;
}

// A-fragment row slice: 8 bf16 from a 31-float vector, zero-padded at k=31.
__device__ __forceinline__ bf16x8 load_avec(const float* __restrict__ p, int k0) {
    bf16x8 r;
#pragma unroll
    for (int j = 0; j < 8; ++j) {
        int k = k0 + j;
        r[j] = f2bf(k < VD ? p[k] : 0.0f);
    }
    return r;
}

// One RNN layer step for this wave's 16-batch tile. Returns new h as A-frag.
__device__ __forceinline__ bf16x8 layer_step(
    bf16x8 ax, bf16x8 ah,
    bf16x8 wi0, bf16x8 wi1, bf16x8 wh0, bf16x8 wh1,
    float b0, float b1, short* buf, int n, int quad, int k0)
{
    f32x4 c0 = {b0, b0, b0, b0};
    f32x4 c1 = {b1, b1, b1, b1};
    c0 = __builtin_amdgcn_mfma_f32_16x16x32_bf16(ax, wi0, c0, 0, 0, 0);
    c1 = __builtin_amdgcn_mfma_f32_16x16x32_bf16(ax, wi1, c1, 0, 0, 0);
    c0 = __builtin_amdgcn_mfma_f32_16x16x32_bf16(ah, wh0, c0, 0, 0, 0);
    c1 = __builtin_amdgcn_mfma_f32_16x16x32_bf16(ah, wh1, c1, 0, 0, 0);
#pragma unroll
    for (int r = 0; r < 4; ++r) {
        int row = quad * 4 + r;
        buf[row * LROW + n]      = f2bf(fast_tanh(c0[r]));
        buf[row * LROW + 16 + n] = f2bf(fast_tanh(c1[r]));
    }
    __builtin_amdgcn_wave_barrier();   // keep write->read order; lgkmcnt by compiler
    return *(const bf16x8*)(buf + n * LROW + k0);
}

__global__ __launch_bounds__(256, 1) void rnn_mfma(
    const float* __restrict__ inp,   // [B, T, V]
    const float* __restrict__ h0,    // [L, B, V]
    const float* __restrict__ Wih,   // [L, V, V]
    const float* __restrict__ Whh,   // [L, V, V]
    const float* __restrict__ bih,   // [L, V]
    const float* __restrict__ bhh,   // [L, V]
    const float* __restrict__ Wlin,  // [V, V]
    const float* __restrict__ blin,  // [V]
    float* __restrict__ out,         // [B, V]
    int B)
{
    __shared__ __align__(16) short lds[4][2][LBUF];   // 10 KB/block

    const int wave = threadIdx.x >> 6;
    const int lane = threadIdx.x & 63;
    const int n    = lane & 15;      // MFMA col (N) / batch row (M) index
    const int quad = lane >> 4;      // 0..3
    const int k0   = quad * 8;       // K base for A/B frags
    const int bbase = (blockIdx.x * 4 + wave) * 16;
    if (bbase >= B) return;

    // ---- stationary weight B-fragments (56 VGPRs), loaded once ----
    const float* W0 = Wih;              const float* U0 = Whh;
    const float* W1 = Wih + VD * VD;    const float* U1 = Whh + VD * VD;
    const float* W2 = Wih + 2 * VD * VD; const float* U2 = Whh + 2 * VD * VD;
    const bf16x8 wiA0 = load_wfrag(W0, n, k0),      wiA1 = load_wfrag(W0, n + 16, k0);
    const bf16x8 whA0 = load_wfrag(U0, n, k0),      whA1 = load_wfrag(U0, n + 16, k0);
    const bf16x8 wiB0 = load_wfrag(W1, n, k0),      wiB1 = load_wfrag(W1, n + 16, k0);
    const bf16x8 whB0 = load_wfrag(U1, n, k0),      whB1 = load_wfrag(U1, n + 16, k0);
    const bf16x8 wiC0 = load_wfrag(W2, n, k0),      wiC1 = load_wfrag(W2, n + 16, k0);
    const bf16x8 whC0 = load_wfrag(U2, n, k0),      whC1 = load_wfrag(U2, n + 16, k0);
    const bf16x8 wl0  = load_wfrag(Wlin, n, k0),    wl1  = load_wfrag(Wlin, n + 16, k0);

    // ---- biases per lane's two N columns (pad col 31 -> 0) ----
    const bool hi_ok = (n + 16) < VD;
    const float bsA0 = bih[n] + bhh[n];
    const float bsA1 = hi_ok ? bih[n + 16] + bhh[n + 16] : 0.0f;
    const float bsB0 = bih[VD + n] + bhh[VD + n];
    const float bsB1 = hi_ok ? bih[VD + n + 16] + bhh[VD + n + 16] : 0.0f;
    const float bsC0 = bih[2 * VD + n] + bhh[2 * VD + n];
    const float bsC1 = hi_ok ? bih[2 * VD + n + 16] + bhh[2 * VD + n + 16] : 0.0f;
    const float bl0  = blin[n];
    const float bl1  = hi_ok ? blin[n + 16] : 0.0f;

    // ---- initial hidden states as A-fragments ----
    bf16x8 ah1 = load_avec(h0 + (size_t)(0 * (size_t)B + bbase + n) * VD, k0);
    bf16x8 ah2 = load_avec(h0 + (size_t)(1 * (size_t)B + bbase + n) * VD, k0);
    bf16x8 ah3 = load_avec(h0 + (size_t)(2 * (size_t)B + bbase + n) * VD, k0);

    const float* xrow = inp + (size_t)(bbase + n) * TD * VD;

    int p = 0;
    for (int t = 0; t < TD; ++t) {
        bf16x8 ax = load_avec(xrow + t * VD, k0);
        ah1 = layer_step(ax,  ah1, wiA0, wiA1, whA0, whA1, bsA0, bsA1,
                         lds[wave][p], n, quad, k0); p ^= 1;
        ah2 = layer_step(ah1, ah2, wiB0, wiB1, whB0, whB1, bsB0, bsB1,
                         lds[wave][p], n, quad, k0); p ^= 1;
        ah3 = layer_step(ah2, ah3, wiC0, wiC1, whC0, whC1, bsC0, bsC1,
                         lds[wave][p], n, quad, k0); p ^= 1;
    }

    // ---- final linear + tanh + softmax ----
    f32x4 c0 = {bl0, bl0, bl0, bl0};
    f32x4 c1 = {bl1, bl1, bl1, bl1};
    c0 = __builtin_amdgcn_mfma_f32_16x16x32_bf16(ah3, wl0, c0, 0, 0, 0);
    c1 = __builtin_amdgcn_mfma_f32_16x16x32_bf16(ah3, wl1, c1, 0, 0, 0);

    const bool pad = (n == 15);      // col 16+15 == 31 is the pad neuron
#pragma unroll
    for (int r = 0; r < 4; ++r) {
        float v0 = fast_tanh(c0[r]);
        float v1 = fast_tanh(c1[r]);
        float mx = pad ? v0 : fmaxf(v0, v1);
#pragma unroll
        for (int msk = 1; msk < 16; msk <<= 1)
            mx = fmaxf(mx, __shfl_xor(mx, msk, 16));
        float e0 = __expf(v0 - mx);
        float e1 = pad ? 0.0f : __expf(v1 - mx);
        float s = e0 + e1;
#pragma unroll
        for (int msk = 1; msk < 16; msk <<= 1)
            s += __shfl_xor(s, msk, 16);
        float inv = __builtin_amdgcn_rcpf(s);
        const size_t row = (size_t)(bbase + quad * 4 + r);
        out[row * VD + n] = e0 * inv;
        if (!pad) out[row * VD + 16 + n] = e1 * inv;
    }
}

extern "C" void kernel_launch(void* const* d_in, const int* in_sizes, int n_in,
                              void* d_out, int out_size, void* d_ws, size_t ws_size,
                              hipStream_t stream) {
    const float* inp  = (const float*)d_in[0];
    const float* h0   = (const float*)d_in[1];
    const float* Wih  = (const float*)d_in[2];
    const float* Whh  = (const float*)d_in[3];
    const float* bih  = (const float*)d_in[4];
    const float* bhh  = (const float*)d_in[5];
    const float* Wlin = (const float*)d_in[6];
    const float* blin = (const float*)d_in[7];
    float* out = (float*)d_out;

    const int B = in_sizes[0] / (TD * VD);
    const int grid = (B + 63) / 64;          // 64 batch rows per block (4 waves x 16)
    rnn_mfma<<<grid, 256, 0, stream>>>(inp, h0, Wih, Whh, bih, bhh, Wlin, blin, out, B);
}

// Round 6
// 217.217 us; speedup vs baseline: 66.4167x; 1.1077x over previous
//
#include <hip/hip_runtime.h>
#include <hip/hip_bf16.h>

// Fused 3-layer tanh RNN (B=131072, T=6, V=31) + linear + tanh + softmax
// on mfma_f32_16x16x32_bf16.
//
// R6: R5 (105 us) was latency-bound (VALUBusy 37%, MfmaUtil 3.6%, no pipe
// saturated): the 19-step recurrence chain (MFMA->tanh->LDS->ds_read->MFMA)
// stalls each wave. Changes:
//  1. TWO independent 16-row M-tiles per wave (32 batch rows, 2 chains
//     interleaved) -> tile-B work hides tile-A ds_read latency in-wave.
//  2. x/h0 fragment loads: 2x dwordx4 instead of 8 guarded dwords (quad 3
//     loads floats 23..30 -- always in-bounds -- and shifts by one).
//     Next-t x prefetched as raw floats across the 6 layer-steps.
//  3. Packed bf16 converts via __float22bfloat162_rn.
// Launch bounds stay (256,1): (256,2) caps VGPR at 128 -> catastrophic
// spill (R1/R3/R4). Watch WRITE_SIZE == 15.9 MB as the no-spill signature.

#define VD 31
#define TD 6
#define LROW 40                 // LDS row stride in shorts (80 B)
#define LBUF (16 * LROW)        // 640 shorts = 1280 B per buffer

typedef __attribute__((ext_vector_type(8))) short bf16x8;
typedef __attribute__((ext_vector_type(4))) float f32x4;
typedef __attribute__((ext_vector_type(4))) unsigned u32x4;
typedef float f32x4u __attribute__((ext_vector_type(4), aligned(4)));

struct raw8 { f32x4u a, b; };

__device__ __forceinline__ short f2bf(float f) {
    unsigned u = __float_as_uint(f);
    unsigned r = (u + 0x7fffu + ((u >> 16) & 1u)) >> 16;
    return (short)r;
}

// packed RNE fp32x2 -> bf16x2 (low = lo, high = hi)
__device__ __forceinline__ unsigned f2bf2u(float lo, float hi) {
    union { __hip_bfloat162 h2; unsigned u; } cvt;
    cvt.h2 = __float22bfloat162_rn(make_float2(lo, hi));
    return cvt.u;
}

__device__ __forceinline__ float fast_tanh(float x) {
    x = fminf(fmaxf(x, -15.0f), 15.0f);
    float e = __expf(2.0f * x);
    return (e - 1.0f) * __builtin_amdgcn_rcpf(e + 1.0f);
}

// raw 8-float load at fo = quad3 ? 23 : quad*8 (always in-bounds, 4B aligned)
__device__ __forceinline__ raw8 load_raw(const float* __restrict__ p, int fo) {
    raw8 r;
    r.a = *(const f32x4u*)(p + fo);
    r.b = *(const f32x4u*)(p + fo + 4);
    return r;
}

// convert raw floats to A-fragment; quad 3 shifts by one and pads k=31 with 0
__device__ __forceinline__ bf16x8 cvt_frag(raw8 r, bool q3) {
    float l[8] = {r.a[0], r.a[1], r.a[2], r.a[3], r.b[0], r.b[1], r.b[2], r.b[3]};
    float s[8];
#pragma unroll
    for (int j = 0; j < 7; ++j) s[j] = q3 ? l[j + 1] : l[j];
    s[7] = q3 ? 0.0f : l[7];
    union { u32x4 u4; bf16x8 b8; } cvt;
#pragma unroll
    for (int j = 0; j < 4; ++j) cvt.u4[j] = f2bf2u(s[2 * j], s[2 * j + 1]);
    return cvt.b8;
}

// B-fragment of W^T (B[k][n] = W[n][k]); rows n>=31 and cols k>=31 zero.
__device__ __forceinline__ bf16x8 load_wfrag(const float* __restrict__ W,
                                             int nn, int k0) {
    bf16x8 r;
#pragma unroll
    for (int j = 0; j < 8; ++j) {
        int k = k0 + j;
        float v = (nn < VD && k < VD) ? W[nn * VD + k] : 0.0f;
        r[j] = f2bf(v);
    }
    return r;
}

// One RNN layer step for one 16-row tile. Returns new h as A-frag.
__device__ __forceinline__ bf16x8 layer_step(
    bf16x8 ax, bf16x8 ah,
    bf16x8 wi0, bf16x8 wi1, bf16x8 wh0, bf16x8 wh1,
    float b0, float b1, short* buf, int n, int quad, int k0)
{
    f32x4 c0 = {b0, b0, b0, b0};
    f32x4 c1 = {b1, b1, b1, b1};
    c0 = __builtin_amdgcn_mfma_f32_16x16x32_bf16(ax, wi0, c0, 0, 0, 0);
    c1 = __builtin_amdgcn_mfma_f32_16x16x32_bf16(ax, wi1, c1, 0, 0, 0);
    c0 = __builtin_amdgcn_mfma_f32_16x16x32_bf16(ah, wh0, c0, 0, 0, 0);
    c1 = __builtin_amdgcn_mfma_f32_16x16x32_bf16(ah, wh1, c1, 0, 0, 0);
#pragma unroll
    for (int r = 0; r < 4; ++r) {
        int row = quad * 4 + r;
        unsigned u = f2bf2u(fast_tanh(c0[r]), fast_tanh(c1[r]));
        buf[row * LROW + n]      = (short)u;
        buf[row * LROW + 16 + n] = (short)(u >> 16);
    }
    __builtin_amdgcn_wave_barrier();   // keep write->read program order
    return *(const bf16x8*)(buf + n * LROW + k0);
}

__global__ __launch_bounds__(256, 1) void rnn_mfma(
    const float* __restrict__ inp,   // [B, T, V]
    const float* __restrict__ h0,    // [L, B, V]
    const float* __restrict__ Wih,   // [L, V, V]
    const float* __restrict__ Whh,   // [L, V, V]
    const float* __restrict__ bih,   // [L, V]
    const float* __restrict__ bhh,   // [L, V]
    const float* __restrict__ Wlin,  // [V, V]
    const float* __restrict__ blin,  // [V]
    float* __restrict__ out,         // [B, V]
    int B)
{
    __shared__ __align__(16) short lds[4][2][2][LBUF];   // 20 KB/block

    const int wave = threadIdx.x >> 6;
    const int lane = threadIdx.x & 63;
    const int n    = lane & 15;
    const int quad = lane >> 4;
    const int k0   = quad * 8;
    const bool q3  = (quad == 3);
    const int fo   = q3 ? 23 : k0;
    const int bbase = (blockIdx.x * 4 + wave) * 32;   // 32 rows per wave
    if (bbase >= B) return;

    // ---- stationary weight B-fragments (56 VGPRs), loaded once ----
    const float* W0 = Wih;               const float* U0 = Whh;
    const float* W1 = Wih + VD * VD;     const float* U1 = Whh + VD * VD;
    const float* W2 = Wih + 2 * VD * VD; const float* U2 = Whh + 2 * VD * VD;
    const bf16x8 wiA0 = load_wfrag(W0, n, k0),   wiA1 = load_wfrag(W0, n + 16, k0);
    const bf16x8 whA0 = load_wfrag(U0, n, k0),   whA1 = load_wfrag(U0, n + 16, k0);
    const bf16x8 wiB0 = load_wfrag(W1, n, k0),   wiB1 = load_wfrag(W1, n + 16, k0);
    const bf16x8 whB0 = load_wfrag(U1, n, k0),   whB1 = load_wfrag(U1, n + 16, k0);
    const bf16x8 wiC0 = load_wfrag(W2, n, k0),   wiC1 = load_wfrag(W2, n + 16, k0);
    const bf16x8 whC0 = load_wfrag(U2, n, k0),   whC1 = load_wfrag(U2, n + 16, k0);
    const bf16x8 wl0  = load_wfrag(Wlin, n, k0), wl1  = load_wfrag(Wlin, n + 16, k0);

    // ---- biases per lane's two N columns (pad col 31 -> 0) ----
    const bool hi_ok = (n + 16) < VD;
    const float bsA0 = bih[n] + bhh[n];
    const float bsA1 = hi_ok ? bih[n + 16] + bhh[n + 16] : 0.0f;
    const float bsB0 = bih[VD + n] + bhh[VD + n];
    const float bsB1 = hi_ok ? bih[VD + n + 16] + bhh[VD + n + 16] : 0.0f;
    const float bsC0 = bih[2 * VD + n] + bhh[2 * VD + n];
    const float bsC1 = hi_ok ? bih[2 * VD + n + 16] + bhh[2 * VD + n + 16] : 0.0f;
    const float bl0  = blin[n];
    const float bl1  = hi_ok ? blin[n + 16] : 0.0f;

    // ---- initial hidden states as A-fragments (tiles a: +0, b: +16) ----
    bf16x8 a1a = cvt_frag(load_raw(h0 + ((size_t)0 * B + bbase + n) * VD, fo), q3);
    bf16x8 a1b = cvt_frag(load_raw(h0 + ((size_t)0 * B + bbase + 16 + n) * VD, fo), q3);
    bf16x8 a2a = cvt_frag(load_raw(h0 + ((size_t)1 * B + bbase + n) * VD, fo), q3);
    bf16x8 a2b = cvt_frag(load_raw(h0 + ((size_t)1 * B + bbase + 16 + n) * VD, fo), q3);
    bf16x8 a3a = cvt_frag(load_raw(h0 + ((size_t)2 * B + bbase + n) * VD, fo), q3);
    bf16x8 a3b = cvt_frag(load_raw(h0 + ((size_t)2 * B + bbase + 16 + n) * VD, fo), q3);

    const float* xrow0 = inp + (size_t)(bbase + n) * TD * VD;
    const float* xrow1 = inp + (size_t)(bbase + 16 + n) * TD * VD;

    raw8 rx0 = load_raw(xrow0, fo);
    raw8 rx1 = load_raw(xrow1, fo);

    int p = 0;
    for (int t = 0; t < TD; ++t) {
        bf16x8 ax0 = cvt_frag(rx0, q3);
        bf16x8 ax1 = cvt_frag(rx1, q3);
        if (t + 1 < TD) {   // prefetch next-t raw x across the 6 steps below
            rx0 = load_raw(xrow0 + (t + 1) * VD, fo);
            rx1 = load_raw(xrow1 + (t + 1) * VD, fo);
        }
        a1a = layer_step(ax0, a1a, wiA0, wiA1, whA0, whA1, bsA0, bsA1,
                         lds[wave][0][p], n, quad, k0);
        a1b = layer_step(ax1, a1b, wiA0, wiA1, whA0, whA1, bsA0, bsA1,
                         lds[wave][1][p], n, quad, k0);
        p ^= 1;
        a2a = layer_step(a1a, a2a, wiB0, wiB1, whB0, whB1, bsB0, bsB1,
                         lds[wave][0][p], n, quad, k0);
        a2b = layer_step(a1b, a2b, wiB0, wiB1, whB0, whB1, bsB0, bsB1,
                         lds[wave][1][p], n, quad, k0);
        p ^= 1;
        a3a = layer_step(a2a, a3a, wiC0, wiC1, whC0, whC1, bsC0, bsC1,
                         lds[wave][0][p], n, quad, k0);
        a3b = layer_step(a2b, a3b, wiC0, wiC1, whC0, whC1, bsC0, bsC1,
                         lds[wave][1][p], n, quad, k0);
        p ^= 1;
    }

    // ---- final linear + tanh + softmax, both tiles ----
    f32x4 c0a = {bl0, bl0, bl0, bl0}, c1a = {bl1, bl1, bl1, bl1};
    f32x4 c0b = {bl0, bl0, bl0, bl0}, c1b = {bl1, bl1, bl1, bl1};
    c0a = __builtin_amdgcn_mfma_f32_16x16x32_bf16(a3a, wl0, c0a, 0, 0, 0);
    c1a = __builtin_amdgcn_mfma_f32_16x16x32_bf16(a3a, wl1, c1a, 0, 0, 0);
    c0b = __builtin_amdgcn_mfma_f32_16x16x32_bf16(a3b, wl0, c0b, 0, 0, 0);
    c1b = __builtin_amdgcn_mfma_f32_16x16x32_bf16(a3b, wl1, c1b, 0, 0, 0);

    const bool pad = (n == 15);          // col 16+15 == 31 is the pad neuron
#pragma unroll
    for (int r = 0; r < 4; ++r) {
#pragma unroll
        for (int tb = 0; tb < 2; ++tb) {
            float v0 = fast_tanh(tb ? c0b[r] : c0a[r]);
            float v1 = fast_tanh(tb ? c1b[r] : c1a[r]);
            float mx = pad ? v0 : fmaxf(v0, v1);
#pragma unroll
            for (int msk = 1; msk < 16; msk <<= 1)
                mx = fmaxf(mx, __shfl_xor(mx, msk, 16));
            float e0 = __expf(v0 - mx);
            float e1 = pad ? 0.0f : __expf(v1 - mx);
            float s = e0 + e1;
#pragma unroll
            for (int msk = 1; msk < 16; msk <<= 1)
                s += __shfl_xor(s, msk, 16);
            float inv = __builtin_amdgcn_rcpf(s);
            const size_t row = (size_t)(bbase + tb * 16 + quad * 4 + r);
            out[row * VD + n] = e0 * inv;
            if (!pad) out[row * VD + 16 + n] = e1 * inv;
        }
    }
}

extern "C" void kernel_launch(void* const* d_in, const int* in_sizes, int n_in,
                              void* d_out, int out_size, void* d_ws, size_t ws_size,
                              hipStream_t stream) {
    const float* inp  = (const float*)d_in[0];
    const float* h0   = (const float*)d_in[1];
    const float* Wih  = (const float*)d_in[2];
    const float* Whh  = (const float*)d_in[3];
    const float* bih  = (const float*)d_in[4];
    const float* bhh  = (const float*)d_in[5];
    const float* Wlin = (const float*)d_in[6];
    const float* blin = (const float*)d_in[7];
    float* out = (float*)d_out;

    const int B = in_sizes[0] / (TD * VD);
    const int grid = (B + 127) / 128;    // 128 rows per block (4 waves x 32)
    rnn_mfma<<<grid, 256, 0, stream>>>(inp, h0, Wih, Whh, bih, bhh, Wlin, blin, out, B);
}